// Round 10
// baseline (298.820 us; speedup 1.0000x reference)
//
#include <hip/hip_runtime.h>
#include <hip/hip_cooperative_groups.h>
#include <math.h>

namespace cg = cooperative_groups;

#define DV   256      // d_model
#define BB   64       // batch
#define LL   512      // seq len
#define DEG2 16       // 2 * n_degree
#define VV   8000     // vocab
#define CC   4        // n_category
#define LPW  4        // l's per wave per unit
#define NW   4        // waves per block
#define UPB  2        // lc-units per block (fused path)
#define NU   16       // lc-unit pairs -> h_part second dim (fused)
#define NLC  32       // lc-chunks (fallback path)
#define NBLK 1024     // fused grid: 4 blocks/CU -> coop-safe
#define LN_EPS 1e-5f

typedef _Float16 half4 __attribute__((ext_vector_type(4)));
typedef float    f32x4 __attribute__((ext_vector_type(4)));

// ================= FUSED cooperative kernel =================
// 1024 blocks x 256. Each block: batch b = blk>>4, lcPair = blk&15,
// covering l in [lcPair*32, lcPair*32+32).
__global__ void __launch_bounds__(256, 4) fused_kernel(
    const int*   __restrict__ x,
    const int*   __restrict__ nb_x,
    const int*   __restrict__ w_edge,
    const float* __restrict__ emb_w,
    const float* __restrict__ we_table,
    const float* __restrict__ eta_table,
    const float* __restrict__ ln_gamma,
    const float* __restrict__ ln_beta,
    const float* __restrict__ fc_w,
    const float* __restrict__ fc_b,
    half4*       __restrict__ norm_emb,   // ws: [VV*64]
    float*       __restrict__ h_part,     // ws: [BB][NU][DV]
    float*       __restrict__ out)
{
    cg::grid_group grid = cg::this_grid();

    const int blk = blockIdx.x;          // 0..1023
    const int tid = threadIdx.x;
    const int w   = tid >> 6;
    const int ln  = tid & 63;

    const int b      = blk >> 4;         // batch
    const int lcPair = blk & 15;
    // unit u (0/1): wave's 4 l's start at base_u
    const int base0 = b * LL + lcPair * 32 + w * LPW;
    const int base1 = base0 + 16;

    // ---- pre: metadata + random we gathers; latency hides under LN ----
    const int   nbv0 = __builtin_nontemporal_load(nb_x   + base0 * DEG2 + ln);
    const int   eiv0 = __builtin_nontemporal_load(w_edge + base0 * DEG2 + ln);
    const float wev0 = __builtin_nontemporal_load(we_table + eiv0);
    const int   nbv1 = __builtin_nontemporal_load(nb_x   + base1 * DEG2 + ln);
    const int   eiv1 = __builtin_nontemporal_load(w_edge + base1 * DEG2 + ln);
    const float wev1 = __builtin_nontemporal_load(we_table + eiv1);

    int xv0 = 0, xv1 = 0; float etv0 = 0.0f, etv1 = 0.0f;
    if (ln < LPW) {
        xv0 = x[base0 + ln]; etv0 = eta_table[xv0];
        xv1 = x[base1 + ln]; etv1 = eta_table[xv1];
    }

    // ---- phase A: LayerNorm two table rows per wave ----
    #pragma unroll
    for (int r = 0; r < 2; ++r) {
        const int row = blk * 8 + w * 2 + r;   // 0..8191
        if (row < VV) {
            const f32x4 v = ((const f32x4*)(emb_w + row * DV))[ln];

            float s = v[0] + v[1] + v[2] + v[3];
            #pragma unroll
            for (int off = 32; off > 0; off >>= 1) s += __shfl_xor(s, off);
            const float mu = s * (1.0f / DV);

            f32x4 c;
            #pragma unroll
            for (int k = 0; k < 4; ++k) c[k] = v[k] - mu;

            float q = c[0]*c[0] + c[1]*c[1] + c[2]*c[2] + c[3]*c[3];
            #pragma unroll
            for (int off = 32; off > 0; off >>= 1) q += __shfl_xor(q, off);
            const float rs = rsqrtf(q * (1.0f / DV) + LN_EPS);

            const f32x4 g  = ((const f32x4*)ln_gamma)[ln];
            const f32x4 bt = ((const f32x4*)ln_beta)[ln];

            half4 h;
            #pragma unroll
            for (int k = 0; k < 4; ++k) h[k] = (_Float16)(c[k] * rs * g[k] + bt[k]);
            norm_emb[row * 64 + ln] = h;
        }
    }

    grid.sync();   // table ready device-wide

    // ---- phase B: row gathers + packed-fp16 weighted max + blend, both units ----
    f32x4 acc = {0.0f, 0.0f, 0.0f, 0.0f};

    #pragma unroll
    for (int u = 0; u < UPB; ++u) {
        const int   nbv = u ? nbv1 : nbv0;
        const float wev = u ? wev1 : wev0;
        const int   xvu = u ? xv1  : xv0;
        const float etu = u ? etv1 : etv0;

        #pragma unroll
        for (int li = 0; li < LPW; ++li) {
            half4 m;
            m[0] = m[1] = m[2] = m[3] = (_Float16)(-65504.0f);

            #pragma unroll
            for (int j = 0; j < DEG2; ++j) {
                const int   lane = li * DEG2 + j;
                const int   idx  = __shfl(nbv, lane);
                const float wej  = __shfl(wev, lane);
                half4 w4; w4[0] = w4[1] = w4[2] = w4[3] = (_Float16)wej;
                const half4 e = norm_emb[idx * 64 + ln];
                m = __builtin_elementwise_max(m, w4 * e);
            }

            const int   sidx = __shfl(xvu, li);
            const float eta  = __shfl(etu, li);
            const half4 se   = norm_emb[sidx * 64 + ln];
            const float om   = 1.0f - eta;
            #pragma unroll
            for (int k = 0; k < 4; ++k)
                acc[k] += om * (float)m[k] + eta * (float)se[k];
        }
    }

    // ---- phase C: block reduce -> h_part[b][lcPair] ----
    __shared__ float s_acc[NW][DV];
    ((f32x4*)s_acc[w])[ln] = acc;
    __syncthreads();
    if (w == 0) {
        f32x4 r0 = ((f32x4*)s_acc[0])[ln];
        f32x4 r1 = ((f32x4*)s_acc[1])[ln];
        f32x4 r2 = ((f32x4*)s_acc[2])[ln];
        f32x4 r3 = ((f32x4*)s_acc[3])[ln];
        f32x4 r;
        #pragma unroll
        for (int k = 0; k < 4; ++k) r[k] = r0[k] + r1[k] + r2[k] + r3[k];
        ((f32x4*)(h_part + (size_t)(b * NU + lcPair) * DV))[ln] = r;
    }

    grid.sync();   // all h_part visible

    // ---- phase D: blocks 0..63 reduce over units and apply FC ----
    if (blk >= BB) return;

    const int d = tid;                    // 0..255
    float h = 0.0f;
    #pragma unroll 8
    for (int q2 = 0; q2 < NU; ++q2)
        h += h_part[(size_t)(blk * NU + q2) * DV + d];

    float p[CC];
    #pragma unroll
    for (int c = 0; c < CC; ++c) p[c] = h * fc_w[d * CC + c];

    #pragma unroll
    for (int c = 0; c < CC; ++c)
        #pragma unroll
        for (int off = 32; off > 0; off >>= 1) p[c] += __shfl_xor(p[c], off);

    __shared__ float s_red[NW][CC];
    if (ln == 0) {
        #pragma unroll
        for (int c = 0; c < CC; ++c) s_red[w][c] = p[c];
    }
    __syncthreads();
    if (d < CC)
        out[blk * CC + d] = s_red[0][d] + s_red[1][d] + s_red[2][d] + s_red[3][d] + fc_b[d];
}

// ================= FALLBACK 3-kernel pipeline (proven R5) =================
__global__ void __launch_bounds__(64) ln_rows_kernel(
    const float* __restrict__ emb, const float* __restrict__ gamma,
    const float* __restrict__ beta, half4* __restrict__ out)
{
    const int row = blockIdx.x;
    const int ln  = threadIdx.x;

    const f32x4 v = ((const f32x4*)(emb + row * DV))[ln];

    float s = v[0] + v[1] + v[2] + v[3];
    #pragma unroll
    for (int off = 32; off > 0; off >>= 1) s += __shfl_xor(s, off);
    const float mu = s * (1.0f / DV);

    f32x4 c;
    #pragma unroll
    for (int k = 0; k < 4; ++k) c[k] = v[k] - mu;

    float q = c[0]*c[0] + c[1]*c[1] + c[2]*c[2] + c[3]*c[3];
    #pragma unroll
    for (int off = 32; off > 0; off >>= 1) q += __shfl_xor(q, off);
    const float rs = rsqrtf(q * (1.0f / DV) + LN_EPS);

    const f32x4 g  = ((const f32x4*)gamma)[ln];
    const f32x4 bt = ((const f32x4*)beta)[ln];

    half4 h;
    #pragma unroll
    for (int k = 0; k < 4; ++k) h[k] = (_Float16)(c[k] * rs * g[k] + bt[k]);
    out[row * 64 + ln] = h;
}

__global__ void __launch_bounds__(256) gnn_kernel(
    const int*   __restrict__ nb_x,
    const int*   __restrict__ w_edge,
    const float* __restrict__ we_table,
    const int*   __restrict__ x,
    const float* __restrict__ eta_table,
    const half4* __restrict__ norm_emb,
    float*       __restrict__ h_part)     // [BB][NLC][DV]
{
    const int b   = blockIdx.x;
    const int lc  = blockIdx.y;
    const int tid = threadIdx.x;
    const int w   = tid >> 6;
    const int ln  = tid & 63;

    const int l0   = lc * 16 + w * LPW;
    const int base = b * LL + l0;

    const int   nbv = __builtin_nontemporal_load(nb_x   + base * DEG2 + ln);
    const int   eiv = __builtin_nontemporal_load(w_edge + base * DEG2 + ln);
    const float wev = __builtin_nontemporal_load(we_table + eiv);

    int xv = 0; float etv = 0.0f;
    if (ln < LPW) { xv = x[base + ln]; etv = eta_table[xv]; }

    f32x4 acc = {0.0f, 0.0f, 0.0f, 0.0f};

    #pragma unroll
    for (int li = 0; li < LPW; ++li) {
        half4 m;
        m[0] = m[1] = m[2] = m[3] = (_Float16)(-65504.0f);

        #pragma unroll
        for (int j = 0; j < DEG2; ++j) {
            const int   lane = li * DEG2 + j;
            const int   idx  = __shfl(nbv, lane);
            const float wej  = __shfl(wev, lane);
            half4 w4; w4[0] = w4[1] = w4[2] = w4[3] = (_Float16)wej;
            const half4 e = norm_emb[idx * 64 + ln];
            m = __builtin_elementwise_max(m, w4 * e);
        }

        const int   sidx = __shfl(xv, li);
        const float eta  = __shfl(etv, li);
        const half4 se   = norm_emb[sidx * 64 + ln];
        const float om   = 1.0f - eta;
        #pragma unroll
        for (int k = 0; k < 4; ++k)
            acc[k] += om * (float)m[k] + eta * (float)se[k];
    }

    __shared__ float s_acc[NW][DV];
    ((f32x4*)s_acc[w])[ln] = acc;
    __syncthreads();
    if (w == 0) {
        f32x4 r0 = ((f32x4*)s_acc[0])[ln];
        f32x4 r1 = ((f32x4*)s_acc[1])[ln];
        f32x4 r2 = ((f32x4*)s_acc[2])[ln];
        f32x4 r3 = ((f32x4*)s_acc[3])[ln];
        f32x4 r;
        #pragma unroll
        for (int k = 0; k < 4; ++k) r[k] = r0[k] + r1[k] + r2[k] + r3[k];
        ((f32x4*)(h_part + (size_t)(b * NLC + lc) * DV))[ln] = r;
    }
}

__global__ void __launch_bounds__(256) fc_kernel(
    const float* __restrict__ h_part,   // [BB][NLC][DV]
    const float* __restrict__ fc_w,
    const float* __restrict__ fc_b,
    float*       __restrict__ out)
{
    const int b  = blockIdx.x;
    const int d  = threadIdx.x;
    const int w  = d >> 6;
    const int ln = d & 63;

    float h = 0.0f;
    #pragma unroll 8
    for (int lc = 0; lc < NLC; ++lc)
        h += h_part[(size_t)(b * NLC + lc) * DV + d];

    float p[CC];
    #pragma unroll
    for (int c = 0; c < CC; ++c) p[c] = h * fc_w[d * CC + c];

    #pragma unroll
    for (int c = 0; c < CC; ++c)
        #pragma unroll
        for (int off = 32; off > 0; off >>= 1) p[c] += __shfl_xor(p[c], off);

    __shared__ float s_red[NW][CC];
    if (ln == 0) {
        #pragma unroll
        for (int c = 0; c < CC; ++c) s_red[w][c] = p[c];
    }
    __syncthreads();
    if (d < CC)
        out[b * CC + d] = s_red[0][d] + s_red[1][d] + s_red[2][d] + s_red[3][d] + fc_b[d];
}

extern "C" void kernel_launch(void* const* d_in, const int* in_sizes, int n_in,
                              void* d_out, int out_size, void* d_ws, size_t ws_size,
                              hipStream_t stream) {
    const int*   x        = (const int*)  d_in[0];
    const int*   nb_x     = (const int*)  d_in[1];
    const int*   w_edge   = (const int*)  d_in[2];
    const float* emb_w    = (const float*)d_in[3];
    const float* we_table = (const float*)d_in[4];
    const float* eta_tab  = (const float*)d_in[5];
    const float* ln_gamma = (const float*)d_in[6];
    const float* ln_beta  = (const float*)d_in[7];
    const float* fc_w     = (const float*)d_in[8];
    const float* fc_b     = (const float*)d_in[9];
    float* out = (float*)d_out;

    // workspace layout (h_part area is large enough for both layouts)
    char* ws = (char*)d_ws;
    half4* norm_emb = (half4*)(ws);                 // 8000*64*8  = 4,096,000 B
    float* h_part   = (float*)(ws + 4096000);       // up to 64*32*256*4 = 2,097,152 B

    void* args[] = {
        (void*)&x, (void*)&nb_x, (void*)&w_edge, (void*)&emb_w,
        (void*)&we_table, (void*)&eta_tab, (void*)&ln_gamma, (void*)&ln_beta,
        (void*)&fc_w, (void*)&fc_b,
        (void*)&norm_emb, (void*)&h_part, (void*)&out
    };
    hipError_t err = hipLaunchCooperativeKernel((const void*)fused_kernel,
                                                dim3(NBLK), dim3(256), args, 0, stream);
    if (err != hipSuccess) {
        (void)hipGetLastError();   // clear sticky error, take the proven path
        ln_rows_kernel<<<VV, 64, 0, stream>>>(emb_w, ln_gamma, ln_beta, norm_emb);
        dim3 grid2(BB, NLC);
        gnn_kernel<<<grid2, 256, 0, stream>>>(nb_x, w_edge, we_table, x, eta_tab,
                                              norm_emb, h_part);
        fc_kernel<<<BB, 256, 0, stream>>>(h_part, fc_w, fc_b, out);
    }
}

// Round 11
// 43.902 us; speedup vs baseline: 6.8066x; 6.8066x over previous
//
#include <hip/hip_runtime.h>
#include <math.h>

#define DV   256      // d_model
#define BB   64       // batch
#define LL   512      // seq len
#define DEG2 16       // 2 * n_degree
#define VV   8000     // vocab
#define CC   4        // n_category
#define LPW  4        // l's per wave
#define NW   4        // waves per block
#define NLC  32       // L-chunks (16 l per block)
#define LN_EPS 1e-5f

typedef _Float16 half4 __attribute__((ext_vector_type(4)));
typedef _Float16 half8 __attribute__((ext_vector_type(8)));
typedef float    f32x4 __attribute__((ext_vector_type(4)));
typedef int      i32x4 __attribute__((ext_vector_type(4)));

__device__ __forceinline__ int rl(int v, int lane) {
    return __builtin_amdgcn_readlane(v, lane);
}
__device__ __forceinline__ float rlf(float v, int lane) {
    return __int_as_float(__builtin_amdgcn_readlane(__float_as_int(v), lane));
}
__device__ __forceinline__ half8 swap32h8(half8 v) {
    i32x4 i = __builtin_bit_cast(i32x4, v);
    i32x4 s;
    #pragma unroll
    for (int k = 0; k < 4; ++k) s[k] = __shfl_xor(i[k], 32);
    return __builtin_bit_cast(half8, s);
}

// ---------------- Kernel 1: LN the table once, emit fp16 rows ----------------
__global__ void __launch_bounds__(64) ln_rows_kernel(
    const float* __restrict__ emb, const float* __restrict__ gamma,
    const float* __restrict__ beta, half4* __restrict__ out)
{
    const int row = blockIdx.x;
    const int ln  = threadIdx.x;

    const f32x4 v = ((const f32x4*)(emb + row * DV))[ln];

    float s = v[0] + v[1] + v[2] + v[3];
    #pragma unroll
    for (int off = 32; off > 0; off >>= 1) s += __shfl_xor(s, off);
    const float mu = s * (1.0f / DV);

    f32x4 c;
    #pragma unroll
    for (int k = 0; k < 4; ++k) c[k] = v[k] - mu;

    float q = c[0]*c[0] + c[1]*c[1] + c[2]*c[2] + c[3]*c[3];
    #pragma unroll
    for (int off = 32; off > 0; off >>= 1) q += __shfl_xor(q, off);
    const float rs = rsqrtf(q * (1.0f / DV) + LN_EPS);

    const f32x4 g  = ((const f32x4*)gamma)[ln];
    const f32x4 bt = ((const f32x4*)beta)[ln];

    half4 h;
    #pragma unroll
    for (int k = 0; k < 4; ++k) h[k] = (_Float16)(c[k] * rs * g[k] + bt[k]);
    out[row * 64 + ln] = h;
}

// ---------------- Kernel 2: fused gather + max + blend, 1KB row loads ----------------
// block = (b, lc); 4 waves; wave owns 4 l's (= 64 edges, one per lane).
// Row loads are dwordx4 (16B/lane): lanes 0-31 carry neighbor row j (j=0..7),
// lanes 32-63 carry row j+8 -> 1KB (2 rows) per vmem instruction, 2x bytes per
// outstanding-load queue slot. Halves are max-combined via 4 shfl_xor(32).
__global__ void __launch_bounds__(256) gnn_kernel(
    const int*   __restrict__ nb_x,
    const int*   __restrict__ w_edge,
    const float* __restrict__ we_table,
    const int*   __restrict__ x,
    const float* __restrict__ eta_table,
    const half8* __restrict__ norm_emb,   // [VV*32], 16B chunks
    float*       __restrict__ h_part)     // [BB][NLC][DV]
{
    const int b   = blockIdx.x;
    const int lc  = blockIdx.y;
    const int tid = threadIdx.x;
    const int w   = tid >> 6;
    const int ln  = tid & 63;
    const int c   = ln & 31;              // 16B chunk within a row (d = 8c..8c+7)
    const int hi8 = (ln >> 5) << 3;       // 0 for low half, 8 for high half

    const int l0   = lc * 16 + w * LPW;
    const int base = b * LL + l0;

    // coalesced metadata + the one random we_table gather per lane
    const int   nbv = __builtin_nontemporal_load(nb_x   + base * DEG2 + ln);
    const int   eiv = __builtin_nontemporal_load(w_edge + base * DEG2 + ln);
    const float wev = __builtin_nontemporal_load(we_table + eiv);

    int xv = 0; float etv = 0.0f;
    if (ln < LPW) { xv = x[base + ln]; etv = eta_table[xv]; }

    float acc[8] = {0,0,0,0,0,0,0,0};

    #pragma unroll
    for (int li = 0; li < LPW; ++li) {
        half8 m;
        #pragma unroll
        for (int k = 0; k < 8; ++k) m[k] = (_Float16)(-65504.0f);

        #pragma unroll
        for (int k = 0; k < 8; ++k) {
            const int   jsrc = li * DEG2 + k + hi8;     // per-half source lane
            const int   idx  = __shfl(nbv, jsrc);       // half-uniform (bpermute)
            const float wj   = __shfl(wev, jsrc);
            half8 w8;
            #pragma unroll
            for (int q = 0; q < 8; ++q) w8[q] = (_Float16)wj;
            const half8 e = norm_emb[idx * 32 + c];     // 16B/lane, 2 rows/instr
            m = __builtin_elementwise_max(m, w8 * e);   // 4x pk_mul + pk_max
        }
        m = __builtin_elementwise_max(m, swap32h8(m));  // combine the two halves

        const int   sidx = rl(xv, li);                  // wave-uniform self row
        const float eta  = rlf(etv, li);
        const half8 se   = norm_emb[sidx * 32 + c];
        const float om   = 1.0f - eta;
        #pragma unroll
        for (int k = 0; k < 8; ++k)
            acc[k] += om * (float)m[k] + eta * (float)se[k];
    }

    // block reduce -> h_part  (low half holds d = 8c..8c+7)
    __shared__ float s_acc[NW][DV];
    if (ln < 32) {
        f32x4 a0 = {acc[0], acc[1], acc[2], acc[3]};
        f32x4 a1 = {acc[4], acc[5], acc[6], acc[7]};
        ((f32x4*)&s_acc[w][c * 8])[0] = a0;
        ((f32x4*)&s_acc[w][c * 8])[1] = a1;
    }
    __syncthreads();
    if (w == 0) {
        f32x4 r0 = ((f32x4*)s_acc[0])[ln];
        f32x4 r1 = ((f32x4*)s_acc[1])[ln];
        f32x4 r2 = ((f32x4*)s_acc[2])[ln];
        f32x4 r3 = ((f32x4*)s_acc[3])[ln];
        f32x4 r;
        #pragma unroll
        for (int k = 0; k < 4; ++k) r[k] = r0[k] + r1[k] + r2[k] + r3[k];
        __builtin_nontemporal_store(r, (f32x4*)(h_part + (size_t)(b * NLC + lc) * DV) + ln);
    }
}

// ---------------- Kernel 3: reduce partials over lc, then FC ----------------
__global__ void __launch_bounds__(256) fc_kernel(
    const float* __restrict__ h_part,
    const float* __restrict__ fc_w,
    const float* __restrict__ fc_b,
    float*       __restrict__ out)
{
    const int b  = blockIdx.x;
    const int d  = threadIdx.x;
    const int w  = d >> 6;
    const int ln = d & 63;

    float h = 0.0f;
    #pragma unroll 8
    for (int lc = 0; lc < NLC; ++lc)
        h += h_part[(size_t)(b * NLC + lc) * DV + d];

    float p[CC];
    #pragma unroll
    for (int c = 0; c < CC; ++c) p[c] = h * fc_w[d * CC + c];

    #pragma unroll
    for (int c = 0; c < CC; ++c)
        #pragma unroll
        for (int off = 32; off > 0; off >>= 1) p[c] += __shfl_xor(p[c], off);

    __shared__ float s_red[NW][CC];
    if (ln == 0) {
        #pragma unroll
        for (int c = 0; c < CC; ++c) s_red[w][c] = p[c];
    }
    __syncthreads();
    if (d < CC)
        out[b * CC + d] = s_red[0][d] + s_red[1][d] + s_red[2][d] + s_red[3][d] + fc_b[d];
}

extern "C" void kernel_launch(void* const* d_in, const int* in_sizes, int n_in,
                              void* d_out, int out_size, void* d_ws, size_t ws_size,
                              hipStream_t stream) {
    const int*   x        = (const int*)  d_in[0];
    const int*   nb_x     = (const int*)  d_in[1];
    const int*   w_edge   = (const int*)  d_in[2];
    const float* emb_w    = (const float*)d_in[3];
    const float* we_table = (const float*)d_in[4];
    const float* eta_tab  = (const float*)d_in[5];
    const float* ln_gamma = (const float*)d_in[6];
    const float* ln_beta  = (const float*)d_in[7];
    const float* fc_w     = (const float*)d_in[8];
    const float* fc_b     = (const float*)d_in[9];
    float* out = (float*)d_out;

    // workspace layout
    char* ws = (char*)d_ws;
    half4* norm_emb = (half4*)(ws);                 // 8000*64*8  = 4,096,000 B
    float* h_part   = (float*)(ws + 4096000);       // 64*32*256*4 = 2,097,152 B

    ln_rows_kernel<<<VV, 64, 0, stream>>>(emb_w, ln_gamma, ln_beta, norm_emb);

    dim3 grid2(BB, NLC);
    gnn_kernel<<<grid2, 256, 0, stream>>>(nb_x, w_edge, we_table, x, eta_tab,
                                          (const half8*)norm_emb, h_part);

    fc_kernel<<<BB, 256, 0, stream>>>(h_part, fc_w, fc_b, out);
}

// Round 13
// 43.115 us; speedup vs baseline: 6.9308x; 1.0183x over previous
//
#include <hip/hip_runtime.h>
#include <math.h>

#define DV   256      // d_model
#define BB   64       // batch
#define LL   512      // seq len
#define DEG2 16       // 2 * n_degree
#define VV   8000     // vocab
#define CC   4        // n_category
#define LPW  4        // l's per wave
#define NW   4        // waves per block
#define NLC  32       // L-chunks (16 l per block)
#define NSL  2        // d-slices
#define NE   (BB*LL*DEG2)   // 524288 edges
#define LN_EPS 1e-5f

typedef _Float16 half4 __attribute__((ext_vector_type(4)));
typedef _Float16 half8 __attribute__((ext_vector_type(8)));
typedef float    f32x2 __attribute__((ext_vector_type(2)));
typedef float    f32x4 __attribute__((ext_vector_type(4)));
typedef int      i32x4 __attribute__((ext_vector_type(4)));

__device__ __forceinline__ half8 sxor_h8(half8 v, int mask) {
    i32x4 i = __builtin_bit_cast(i32x4, v);
    i32x4 s;
    #pragma unroll
    for (int k = 0; k < 4; ++k) s[k] = __shfl_xor(i[k], mask);
    return __builtin_bit_cast(half8, s);
}

// ---------------- Kernel 1: LN the table -> fp16 sliced layout, + we_flat gather ----------------
// table layout: slice s holds d in [s*128, s*128+128) : bytes [( s*VV + row )*256 .. +256)
__global__ void __launch_bounds__(64) ln_rows_kernel(
    const float* __restrict__ emb, const float* __restrict__ gamma,
    const float* __restrict__ beta,
    const int* __restrict__ w_edge, const float* __restrict__ we_table,
    half4* __restrict__ out, float* __restrict__ we_flat)
{
    const int row = blockIdx.x;
    const int ln  = threadIdx.x;

    // ---- random we_table gather, amortized across the grid (latency hides under LN) ----
    for (int g = blockIdx.x * 64 + ln; g < NE; g += VV * 64)
        we_flat[g] = we_table[w_edge[g]];

    const f32x4 v = ((const f32x4*)(emb + row * DV))[ln];

    float s = v[0] + v[1] + v[2] + v[3];
    #pragma unroll
    for (int off = 32; off > 0; off >>= 1) s += __shfl_xor(s, off);
    const float mu = s * (1.0f / DV);

    f32x4 c;
    #pragma unroll
    for (int k = 0; k < 4; ++k) c[k] = v[k] - mu;

    float q = c[0]*c[0] + c[1]*c[1] + c[2]*c[2] + c[3]*c[3];
    #pragma unroll
    for (int off = 32; off > 0; off >>= 1) q += __shfl_xor(q, off);
    const float rs = rsqrtf(q * (1.0f / DV) + LN_EPS);

    const f32x4 g  = ((const f32x4*)gamma)[ln];
    const f32x4 bt = ((const f32x4*)beta)[ln];

    half4 h;
    #pragma unroll
    for (int k = 0; k < 4; ++k) h[k] = (_Float16)(c[k] * rs * g[k] + bt[k]);

    const int sl = ln >> 5;                 // slice
    const int cc = ln & 31;                 // 8B chunk within slice
    ((half4*)out)[((size_t)sl * VV + row) * 32 + cc] = h;
}

// ---------------- Kernel 2: d-sliced gather + max + blend; XCD-pinned slices ----------------
// 4096 blocks: xcd = blk&7 ; slice = xcd>>2 ; (b,lc) from the rest.
// Each XCD touches only its 2MB table slice -> L2-resident.
// Quad-row loads: lane-group q=ln>>4 carries row (k4*4+q), 16 lanes x 16B = 256B slice.
__global__ void __launch_bounds__(256) gnn_kernel(
    const int*   __restrict__ nb_x,
    const int*   __restrict__ x,
    const float* __restrict__ we_flat,
    const float* __restrict__ eta_table,
    const half8* __restrict__ norm_emb,   // [NSL][VV][16 chunks of 16B]
    float*       __restrict__ h_part)     // [BB][NLC][DV]
{
    const int blk = blockIdx.x;
    const int xcd = blk & 7;
    const int u   = blk >> 3;
    const int sl  = xcd >> 2;                  // slice for this XCD
    const int qq  = (xcd & 3) + (u << 2);      // 0..2047
    const int b   = qq >> 5;
    const int lc  = qq & 31;

    const int tid = threadIdx.x;
    const int w   = tid >> 6;
    const int ln  = tid & 63;
    const int q   = ln >> 4;                   // lane group = row-within-quad
    const int c8  = ln & 15;                   // 16B chunk within row slice

    const int l0   = lc * 16 + w * LPW;
    const int base = b * LL + l0;
    const size_t sRow = (size_t)sl * VV;       // row offset of slice

    // coalesced metadata (nt: keep L2 for the table slice)
    const int   nbv = __builtin_nontemporal_load(nb_x    + base * DEG2 + ln);
    const float wev = __builtin_nontemporal_load(we_flat + base * DEG2 + ln);

    int xv = 0; float etv = 0.0f;
    if (ln < LPW) { xv = x[base + ln]; etv = eta_table[xv]; }

    // self rows: one quad load serves the wave's 4 l's (group q -> l = l0+q)
    // NOTE: q is divergent -> must use __shfl (ds_bpermute), NOT readlane.
    const int   srow = __shfl(xv, q);
    const half8 se   = norm_emb[(sRow + srow) * 16 + c8];
    const float eta  = __shfl(etv, q);
    const float om   = 1.0f - eta;

    float acc[8] = {0,0,0,0,0,0,0,0};

    #pragma unroll
    for (int li = 0; li < LPW; ++li) {
        half8 m;
        #pragma unroll
        for (int k = 0; k < 8; ++k) m[k] = (_Float16)(-65504.0f);

        #pragma unroll
        for (int k4 = 0; k4 < 4; ++k4) {
            const int   jsrc = li * DEG2 + k4 * 4 + q;   // per-group source lane
            const int   idx  = __shfl(nbv, jsrc);
            const float wj   = __shfl(wev, jsrc);
            half8 w8;
            #pragma unroll
            for (int t = 0; t < 8; ++t) w8[t] = (_Float16)wj;
            const half8 e = norm_emb[(sRow + idx) * 16 + c8];   // 4 rows / instr
            m = __builtin_elementwise_max(m, w8 * e);
        }
        // combine the 4 lane-groups' partial maxima
        m = __builtin_elementwise_max(m, sxor_h8(m, 16));
        m = __builtin_elementwise_max(m, sxor_h8(m, 32));

        // group q accumulates its own l (q == li)
        if (q == li) {
            #pragma unroll
            for (int k = 0; k < 8; ++k)
                acc[k] += om * (float)m[k] + eta * (float)se[k];
        }
    }

    // sum the 4 groups (= the wave's 4 l's)
    #pragma unroll
    for (int k = 0; k < 8; ++k) {
        acc[k] += __shfl_xor(acc[k], 16);
        acc[k] += __shfl_xor(acc[k], 32);
    }

    // block reduce across waves for this slice's 128 d
    __shared__ float s_acc[NW][DV / NSL];
    if (ln < 16) {
        f32x4 a0 = {acc[0], acc[1], acc[2], acc[3]};
        f32x4 a1 = {acc[4], acc[5], acc[6], acc[7]};
        ((f32x4*)&s_acc[w][c8 * 8])[0] = a0;
        ((f32x4*)&s_acc[w][c8 * 8])[1] = a1;
    }
    __syncthreads();
    if (w == 0) {
        const int d2 = ln * 2;                  // 2 floats per lane (128 total)
        f32x2 r;
        r[0] = s_acc[0][d2]     + s_acc[1][d2]     + s_acc[2][d2]     + s_acc[3][d2];
        r[1] = s_acc[0][d2 + 1] + s_acc[1][d2 + 1] + s_acc[2][d2 + 1] + s_acc[3][d2 + 1];
        __builtin_nontemporal_store(r,
            (f32x2*)(h_part + (size_t)(b * NLC + lc) * DV + sl * (DV / NSL)) + ln);
    }
}

// ---------------- Kernel 3: reduce partials over lc, then FC ----------------
__global__ void __launch_bounds__(256) fc_kernel(
    const float* __restrict__ h_part,
    const float* __restrict__ fc_w,
    const float* __restrict__ fc_b,
    float*       __restrict__ out)
{
    const int b  = blockIdx.x;
    const int d  = threadIdx.x;
    const int w  = d >> 6;
    const int ln = d & 63;

    float h = 0.0f;
    #pragma unroll 8
    for (int lc = 0; lc < NLC; ++lc)
        h += h_part[(size_t)(b * NLC + lc) * DV + d];

    float p[CC];
    #pragma unroll
    for (int c = 0; c < CC; ++c) p[c] = h * fc_w[d * CC + c];

    #pragma unroll
    for (int c = 0; c < CC; ++c)
        #pragma unroll
        for (int off = 32; off > 0; off >>= 1) p[c] += __shfl_xor(p[c], off);

    __shared__ float s_red[NW][CC];
    if (ln == 0) {
        #pragma unroll
        for (int c = 0; c < CC; ++c) s_red[w][c] = p[c];
    }
    __syncthreads();
    if (d < CC)
        out[b * CC + d] = s_red[0][d] + s_red[1][d] + s_red[2][d] + s_red[3][d] + fc_b[d];
}

extern "C" void kernel_launch(void* const* d_in, const int* in_sizes, int n_in,
                              void* d_out, int out_size, void* d_ws, size_t ws_size,
                              hipStream_t stream) {
    const int*   x        = (const int*)  d_in[0];
    const int*   nb_x     = (const int*)  d_in[1];
    const int*   w_edge   = (const int*)  d_in[2];
    const float* emb_w    = (const float*)d_in[3];
    const float* we_table = (const float*)d_in[4];
    const float* eta_tab  = (const float*)d_in[5];
    const float* ln_gamma = (const float*)d_in[6];
    const float* ln_beta  = (const float*)d_in[7];
    const float* fc_w     = (const float*)d_in[8];
    const float* fc_b     = (const float*)d_in[9];
    float* out = (float*)d_out;

    // workspace layout
    char* ws = (char*)d_ws;
    half4* norm_emb = (half4*)(ws);                      // 2*8000*256 = 4,096,000 B
    float* we_flat  = (float*)(ws + 4096000);            // 524288*4   = 2,097,152 B
    float* h_part   = (float*)(ws + 4096000 + 2097152);  // 64*32*256*4 = 2,097,152 B

    ln_rows_kernel<<<VV, 64, 0, stream>>>(emb_w, ln_gamma, ln_beta,
                                          w_edge, we_table, norm_emb, we_flat);

    gnn_kernel<<<BB * NLC * NSL, 256, 0, stream>>>(
        nb_x, x, we_flat, eta_tab, (const half8*)norm_emb, h_part);

    fc_kernel<<<BB, 256, 0, stream>>>(h_part, fc_w, fc_b, out);
}